// Round 1
// baseline (316.477 us; speedup 1.0000x reference)
//
#include <hip/hip_runtime.h>
#include <hip/hip_bf16.h>

// Fused: LayerNorm -> QKV proj -> 16-head attention (n=2048, d=64) -> out proj + bias.
// All intermediates fp16 in d_ws (~40 MB). fp32 accumulate everywhere.

typedef _Float16 f16x8 __attribute__((ext_vector_type(8)));
typedef _Float16 f16x4 __attribute__((ext_vector_type(4)));
typedef float    f32x4 __attribute__((ext_vector_type(4)));

#define DIM   1024
#define NH    16
#define HD2   64
#define SEQ   2048
#define ROWS  4096   // b*n = 2*2048
#define QKVN  3072

__device__ __forceinline__ void async_copy16(void* lds, const void* gsrc) {
    __builtin_amdgcn_global_load_lds(
        (const __attribute__((address_space(1))) unsigned int*)gsrc,
        (__attribute__((address_space(3))) unsigned int*)lds, 16, 0, 0);
}

// ---------------- LayerNorm: fp32 (ROWS x DIM) -> f16 ----------------
__global__ __launch_bounds__(256) void ln_kernel(
    const float* __restrict__ x, const float* __restrict__ gamma,
    const float* __restrict__ beta, _Float16* __restrict__ xn) {
    const int row = blockIdx.x;
    const int t = threadIdx.x;
    const float4 v = reinterpret_cast<const float4*>(x + (size_t)row * DIM)[t];
    float s1 = v.x + v.y + v.z + v.w;
    float s2 = v.x * v.x + v.y * v.y + v.z * v.z + v.w * v.w;
    for (int off = 32; off; off >>= 1) {
        s1 += __shfl_down(s1, off);
        s2 += __shfl_down(s2, off);
    }
    __shared__ float red[8];
    const int wv = t >> 6, lane = t & 63;
    if (lane == 0) { red[wv * 2] = s1; red[wv * 2 + 1] = s2; }
    __syncthreads();
    s1 = red[0] + red[2] + red[4] + red[6];
    s2 = red[1] + red[3] + red[5] + red[7];
    const float mu = s1 * (1.0f / DIM);
    const float var = s2 * (1.0f / DIM) - mu * mu;
    const float rstd = rsqrtf(var + 1e-5f);
    const float4 g = reinterpret_cast<const float4*>(gamma)[t];
    const float4 bb = reinterpret_cast<const float4*>(beta)[t];
    f16x4 o;
    o[0] = (_Float16)((v.x - mu) * rstd * g.x + bb.x);
    o[1] = (_Float16)((v.y - mu) * rstd * g.y + bb.y);
    o[2] = (_Float16)((v.z - mu) * rstd * g.z + bb.z);
    o[3] = (_Float16)((v.w - mu) * rstd * g.w + bb.w);
    reinterpret_cast<f16x4*>(xn + (size_t)row * DIM)[t] = o;
}

// ------------- transpose + fp32->f16: in (R x C) -> out (C x R) -------------
__global__ __launch_bounds__(256) void transpose_cvt_kernel(
    const float* __restrict__ in, _Float16* __restrict__ out, int R, int C) {
    __shared__ float tile[32][33];
    const int c0 = blockIdx.x * 32, r0 = blockIdx.y * 32;
    const int tx = threadIdx.x, ty = threadIdx.y;  // (32, 8)
#pragma unroll
    for (int i = 0; i < 4; i++)
        tile[ty + i * 8][tx] = in[(size_t)(r0 + ty + i * 8) * C + c0 + tx];
    __syncthreads();
#pragma unroll
    for (int i = 0; i < 4; i++)
        out[(size_t)(c0 + ty + i * 8) * R + r0 + tx] = (_Float16)tile[tx][ty + i * 8];
}

// ------------- GEMM: A (MxK f16, RM) * Bt (NxK f16, RM) -> C (MxN) -------------
// 128x128 tile, BK=32, 4 waves (2x2 of 64x64), mfma 16x16x32, global_load_lds staging.
template <bool STORE_F32>
__global__ __launch_bounds__(256) void gemm_f16_kernel(
    const _Float16* __restrict__ A, const _Float16* __restrict__ Bt,
    void* __restrict__ Cv, const float* __restrict__ bias, int M, int N, int K) {
    __shared__ _Float16 Al[128 * 32];
    __shared__ _Float16 Bl[128 * 32];
    const int t = threadIdx.x, wv = t >> 6, lane = t & 63;
    const int lg = lane >> 4, lr = lane & 15;
    const int wr = wv >> 1, wc = wv & 1;
    const int m0 = blockIdx.y * 128, n0 = blockIdx.x * 128;

    f32x4 acc[4][4] = {};

    const int srow = t >> 2, sk = (t & 3) * 8;
    const _Float16* Ag0 = A + (size_t)(m0 + srow) * K + sk;
    const _Float16* Bg0 = Bt + (size_t)(n0 + srow) * K + sk;
    _Float16* Alw = Al + wv * 512;  // wave-uniform LDS base (64 lanes x 8 f16)
    _Float16* Blw = Bl + wv * 512;

    for (int k0 = 0; k0 < K; k0 += 32) {
        __syncthreads();
        async_copy16(Alw,        Ag0 + k0);
        async_copy16(Alw + 2048, Ag0 + (size_t)64 * K + k0);
        async_copy16(Blw,        Bg0 + k0);
        async_copy16(Blw + 2048, Bg0 + (size_t)64 * K + k0);
        __syncthreads();
        f16x8 af[4], bfr[4];
#pragma unroll
        for (int m = 0; m < 4; m++)
            af[m] = *reinterpret_cast<const f16x8*>(&Al[(wr * 64 + m * 16 + lr) * 32 + lg * 8]);
#pragma unroll
        for (int n = 0; n < 4; n++)
            bfr[n] = *reinterpret_cast<const f16x8*>(&Bl[(wc * 64 + n * 16 + lr) * 32 + lg * 8]);
#pragma unroll
        for (int m = 0; m < 4; m++)
#pragma unroll
            for (int n = 0; n < 4; n++)
                acc[m][n] = __builtin_amdgcn_mfma_f32_16x16x32_f16(af[m], bfr[n], acc[m][n], 0, 0, 0);
    }

#pragma unroll
    for (int m = 0; m < 4; m++) {
        const int row = m0 + wr * 64 + m * 16 + lg * 4;
#pragma unroll
        for (int n = 0; n < 4; n++) {
            const int col = n0 + wc * 64 + n * 16 + lr;
            float bo = 0.0f;
            if constexpr (STORE_F32) bo = bias[col];
#pragma unroll
            for (int jj = 0; jj < 4; jj++) {
                const float v = acc[m][n][jj];
                if constexpr (STORE_F32)
                    reinterpret_cast<float*>(Cv)[(size_t)(row + jj) * N + col] = v + bo;
                else
                    reinterpret_cast<_Float16*>(Cv)[(size_t)(row + jj) * N + col] = (_Float16)v;
            }
        }
    }
}

// ------------- flash attention: qkv (ROWS x 3072 f16) -> attn (ROWS x 1024 f16) -------------
// grid (32 q-tiles, 32 b*h). block 256 = 4 waves; wave owns 16 q rows; KV tile = 64.
__global__ __launch_bounds__(256) void attn_fa_kernel(
    const _Float16* __restrict__ qkv, _Float16* __restrict__ attn) {
    const int bh = blockIdx.y, b = bh >> 4, h = bh & 15;
    const int q0 = blockIdx.x * 64;
    const int t = threadIdx.x, wv = t >> 6, lane = t & 63;
    const int lg = lane >> 4, lr = lane & 15;

    __shared__ _Float16 Kl[64][72];        // K tile [key][d], +8 pad
    __shared__ _Float16 Vt[64][72];        // V^T tile [d][key], +8 pad
    __shared__ _Float16 Pl[4][16][72];     // per-wave P [row][key]

    // Q fragments (A layout: row=lr, k=8*lg+j), pre-scaled by 1/sqrt(64)
    const size_t qrow = (size_t)(b * SEQ + q0 + wv * 16 + lr);
    const _Float16* qp = qkv + qrow * QKVN + h * HD2;
    f16x8 qf0 = *reinterpret_cast<const f16x8*>(qp + lg * 8);
    f16x8 qf1 = *reinterpret_cast<const f16x8*>(qp + 32 + lg * 8);
    qf0 = qf0 * (_Float16)0.125f;
    qf1 = qf1 * (_Float16)0.125f;

    f32x4 o[4] = {};
    float mrun[4] = {-INFINITY, -INFINITY, -INFINITY, -INFINITY};
    float lrun[4] = {0.f, 0.f, 0.f, 0.f};

    const int sr = t >> 3, sc = (t & 7) * 8;  // staging coords: rows 0..31 (+32), 8 cols

    for (int kv0 = 0; kv0 < SEQ; kv0 += 64) {
        __syncthreads();
        {   // stage K rows sr, sr+32 (vector copies) and V transposed (scalar scatter)
            const _Float16* kp = qkv + (size_t)(b * SEQ + kv0 + sr) * QKVN + DIM + h * HD2 + sc;
            *reinterpret_cast<f16x8*>(&Kl[sr][sc])      = *reinterpret_cast<const f16x8*>(kp);
            *reinterpret_cast<f16x8*>(&Kl[sr + 32][sc]) = *reinterpret_cast<const f16x8*>(kp + (size_t)32 * QKVN);
            const _Float16* vp = kp + DIM;
            f16x8 v0 = *reinterpret_cast<const f16x8*>(vp);
            f16x8 v1 = *reinterpret_cast<const f16x8*>(vp + (size_t)32 * QKVN);
#pragma unroll
            for (int j = 0; j < 8; j++) {
                Vt[sc + j][sr]      = v0[j];
                Vt[sc + j][sr + 32] = v1[j];
            }
        }
        __syncthreads();

        // S = (Q/8) K^T : 4 key-chunks of 16
        f32x4 s[4];
#pragma unroll
        for (int n = 0; n < 4; n++) {
            f16x8 kf0 = *reinterpret_cast<const f16x8*>(&Kl[n * 16 + lr][lg * 8]);
            f16x8 kf1 = *reinterpret_cast<const f16x8*>(&Kl[n * 16 + lr][32 + lg * 8]);
            f32x4 z = {0.f, 0.f, 0.f, 0.f};
            z = __builtin_amdgcn_mfma_f32_16x16x32_f16(qf0, kf0, z, 0, 0, 0);
            z = __builtin_amdgcn_mfma_f32_16x16x32_f16(qf1, kf1, z, 0, 0, 0);
            s[n] = z;
        }

        // online softmax (row r = 4*lg + jj lives in the 16 lanes of group lg)
        float pm[4], corr[4];
#pragma unroll
        for (int jj = 0; jj < 4; jj++) {
            float m1 = fmaxf(fmaxf(s[0][jj], s[1][jj]), fmaxf(s[2][jj], s[3][jj]));
            m1 = fmaxf(m1, __shfl_xor(m1, 1));
            m1 = fmaxf(m1, __shfl_xor(m1, 2));
            m1 = fmaxf(m1, __shfl_xor(m1, 4));
            m1 = fmaxf(m1, __shfl_xor(m1, 8));
            const float mnew = fmaxf(mrun[jj], m1);
            corr[jj] = __expf(mrun[jj] - mnew);
            mrun[jj] = mnew;
            pm[jj] = mnew;
        }
        float rsum[4] = {0.f, 0.f, 0.f, 0.f};
#pragma unroll
        for (int n = 0; n < 4; n++)
#pragma unroll
            for (int jj = 0; jj < 4; jj++) {
                const float p = __expf(s[n][jj] - pm[jj]);
                s[n][jj] = p;
                rsum[jj] += p;
            }
#pragma unroll
        for (int jj = 0; jj < 4; jj++) {
            float r = rsum[jj];
            r += __shfl_xor(r, 1);
            r += __shfl_xor(r, 2);
            r += __shfl_xor(r, 4);
            r += __shfl_xor(r, 8);
            lrun[jj] = lrun[jj] * corr[jj] + r;
        }
#pragma unroll
        for (int dn = 0; dn < 4; dn++)
#pragma unroll
            for (int jj = 0; jj < 4; jj++) o[dn][jj] *= corr[jj];

        // P (D-layout) -> LDS -> A-layout fragments (wave-private, no barrier)
#pragma unroll
        for (int n = 0; n < 4; n++)
#pragma unroll
            for (int jj = 0; jj < 4; jj++)
                Pl[wv][lg * 4 + jj][n * 16 + lr] = (_Float16)s[n][jj];
        f16x8 pa0 = *reinterpret_cast<const f16x8*>(&Pl[wv][lr][lg * 8]);
        f16x8 pa1 = *reinterpret_cast<const f16x8*>(&Pl[wv][lr][32 + lg * 8]);

        // O += P V  (B = V^T[d][key], contiguous keys)
#pragma unroll
        for (int dn = 0; dn < 4; dn++) {
            f16x8 vf0 = *reinterpret_cast<const f16x8*>(&Vt[dn * 16 + lr][lg * 8]);
            f16x8 vf1 = *reinterpret_cast<const f16x8*>(&Vt[dn * 16 + lr][32 + lg * 8]);
            o[dn] = __builtin_amdgcn_mfma_f32_16x16x32_f16(pa0, vf0, o[dn], 0, 0, 0);
            o[dn] = __builtin_amdgcn_mfma_f32_16x16x32_f16(pa1, vf1, o[dn], 0, 0, 0);
        }
    }

    // epilogue: divide by l, store f16
#pragma unroll
    for (int jj = 0; jj < 4; jj++) {
        const float inv = 1.0f / lrun[jj];
        const size_t orow = (size_t)(b * SEQ + q0 + wv * 16 + lg * 4 + jj);
#pragma unroll
        for (int dn = 0; dn < 4; dn++)
            attn[orow * DIM + h * HD2 + dn * 16 + lr] = (_Float16)(o[dn][jj] * inv);
    }
}

extern "C" void kernel_launch(void* const* d_in, const int* in_sizes, int n_in,
                              void* d_out, int out_size, void* d_ws, size_t ws_size,
                              hipStream_t stream) {
    const float* x     = (const float*)d_in[0];
    const float* gamma = (const float*)d_in[1];
    const float* beta  = (const float*)d_in[2];
    const float* w_qkv = (const float*)d_in[3];
    const float* w_out = (const float*)d_in[4];
    const float* b_out = (const float*)d_in[5];
    float* out = (float*)d_out;

    // workspace layout (f16): xn/attn share (attn written after xn consumed)
    _Float16* ws    = (_Float16*)d_ws;
    _Float16* xn    = ws;                                  // 4096*1024
    _Float16* wqkvT = xn + (size_t)ROWS * DIM;             // 3072*1024
    _Float16* woutT = wqkvT + (size_t)QKVN * DIM;          // 1024*1024
    _Float16* qkv   = woutT + (size_t)DIM * DIM;           // 4096*3072
    _Float16* attnb = xn;                                  // reuse xn region

    ln_kernel<<<ROWS, 256, 0, stream>>>(x, gamma, beta, xn);
    transpose_cvt_kernel<<<dim3(QKVN / 32, DIM / 32), dim3(32, 8), 0, stream>>>(w_qkv, wqkvT, DIM, QKVN);
    transpose_cvt_kernel<<<dim3(DIM / 32, DIM / 32), dim3(32, 8), 0, stream>>>(w_out, woutT, DIM, DIM);
    gemm_f16_kernel<false><<<dim3(QKVN / 128, ROWS / 128), 256, 0, stream>>>(
        xn, wqkvT, (void*)qkv, nullptr, ROWS, QKVN, DIM);
    attn_fa_kernel<<<dim3(SEQ / 64, 32), 256, 0, stream>>>(qkv, attnb);
    gemm_f16_kernel<true><<<dim3(DIM / 128, ROWS / 128), 256, 0, stream>>>(
        attnb, woutT, (void*)out, b_out, ROWS, DIM, DIM);
}

// Round 2
// 230.154 us; speedup vs baseline: 1.3751x; 1.3751x over previous
//
#include <hip/hip_runtime.h>
#include <hip/hip_bf16.h>

// Fused: LayerNorm -> QKV proj (V written transposed) -> 16-head attention -> out proj + bias.

typedef _Float16 f16x8 __attribute__((ext_vector_type(8)));
typedef _Float16 f16x4 __attribute__((ext_vector_type(4)));
typedef float    f32x4 __attribute__((ext_vector_type(4)));

#define DIM   1024
#define NH    16
#define HD2   64
#define SEQ   2048
#define ROWS  4096   // b*n = 2*2048
#define QKVN  3072

__device__ __forceinline__ void async_copy16(void* lds, const void* gsrc) {
    __builtin_amdgcn_global_load_lds(
        (const __attribute__((address_space(1))) unsigned int*)gsrc,
        (__attribute__((address_space(3))) unsigned int*)lds, 16, 0, 0);
}

// ---------------- LayerNorm: fp32 (ROWS x DIM) -> f16 ----------------
__global__ __launch_bounds__(256) void ln_kernel(
    const float* __restrict__ x, const float* __restrict__ gamma,
    const float* __restrict__ beta, _Float16* __restrict__ xn) {
    const int row = blockIdx.x;
    const int t = threadIdx.x;
    const float4 v = reinterpret_cast<const float4*>(x + (size_t)row * DIM)[t];
    float s1 = v.x + v.y + v.z + v.w;
    float s2 = v.x * v.x + v.y * v.y + v.z * v.z + v.w * v.w;
    for (int off = 32; off; off >>= 1) {
        s1 += __shfl_down(s1, off);
        s2 += __shfl_down(s2, off);
    }
    __shared__ float red[8];
    const int wv = t >> 6, lane = t & 63;
    if (lane == 0) { red[wv * 2] = s1; red[wv * 2 + 1] = s2; }
    __syncthreads();
    s1 = red[0] + red[2] + red[4] + red[6];
    s2 = red[1] + red[3] + red[5] + red[7];
    const float mu = s1 * (1.0f / DIM);
    const float var = s2 * (1.0f / DIM) - mu * mu;
    const float rstd = rsqrtf(var + 1e-5f);
    const float4 g = reinterpret_cast<const float4*>(gamma)[t];
    const float4 bb = reinterpret_cast<const float4*>(beta)[t];
    f16x4 o;
    o[0] = (_Float16)((v.x - mu) * rstd * g.x + bb.x);
    o[1] = (_Float16)((v.y - mu) * rstd * g.y + bb.y);
    o[2] = (_Float16)((v.z - mu) * rstd * g.z + bb.z);
    o[3] = (_Float16)((v.w - mu) * rstd * g.w + bb.w);
    reinterpret_cast<f16x4*>(xn + (size_t)row * DIM)[t] = o;
}

// ------------- transpose + fp32->f16: in (R x C) -> out (C x R) -------------
__global__ __launch_bounds__(256) void transpose_cvt_kernel(
    const float* __restrict__ in, _Float16* __restrict__ out, int R, int C) {
    __shared__ float tile[32][33];
    const int c0 = blockIdx.x * 32, r0 = blockIdx.y * 32;
    const int tx = threadIdx.x, ty = threadIdx.y;  // (32, 8)
#pragma unroll
    for (int i = 0; i < 4; i++)
        tile[ty + i * 8][tx] = in[(size_t)(r0 + ty + i * 8) * C + c0 + tx];
    __syncthreads();
#pragma unroll
    for (int i = 0; i < 4; i++)
        out[(size_t)(c0 + ty + i * 8) * R + r0 + tx] = (_Float16)tile[tx][ty + i * 8];
}

// ------------- QKV GEMM: xn (4096x1024) * wqkvT (3072x1024) -------------
// Q,K cols (<2048) -> qk[row][col] (ld 2048). V cols (>=2048) -> vT[bh*64+d][n].
__global__ __launch_bounds__(256) void gemm_qkv_kernel(
    const _Float16* __restrict__ A, const _Float16* __restrict__ Bt,
    _Float16* __restrict__ qk, _Float16* __restrict__ vT, int K) {
    __shared__ _Float16 Al[128 * 32];
    __shared__ _Float16 Bl[128 * 32];
    const int t = threadIdx.x, wv = t >> 6, lane = t & 63;
    const int lg = lane >> 4, lr = lane & 15;
    const int wr = wv >> 1, wc = wv & 1;
    const int m0 = blockIdx.y * 128, n0 = blockIdx.x * 128;

    f32x4 acc[4][4] = {};

    const int srow = t >> 2, sk = (t & 3) * 8;
    const _Float16* Ag0 = A + (size_t)(m0 + srow) * K + sk;
    const _Float16* Bg0 = Bt + (size_t)(n0 + srow) * K + sk;
    _Float16* Alw = Al + wv * 512;
    _Float16* Blw = Bl + wv * 512;

    for (int k0 = 0; k0 < K; k0 += 32) {
        __syncthreads();
        async_copy16(Alw,        Ag0 + k0);
        async_copy16(Alw + 2048, Ag0 + (size_t)64 * K + k0);
        async_copy16(Blw,        Bg0 + k0);
        async_copy16(Blw + 2048, Bg0 + (size_t)64 * K + k0);
        __syncthreads();
        f16x8 af[4], bfr[4];
#pragma unroll
        for (int m = 0; m < 4; m++)
            af[m] = *reinterpret_cast<const f16x8*>(&Al[(wr * 64 + m * 16 + lr) * 32 + lg * 8]);
#pragma unroll
        for (int n = 0; n < 4; n++)
            bfr[n] = *reinterpret_cast<const f16x8*>(&Bl[(wc * 64 + n * 16 + lr) * 32 + lg * 8]);
#pragma unroll
        for (int m = 0; m < 4; m++)
#pragma unroll
            for (int n = 0; n < 4; n++)
                acc[m][n] = __builtin_amdgcn_mfma_f32_16x16x32_f16(af[m], bfr[n], acc[m][n], 0, 0, 0);
    }

    if (n0 < 2 * DIM) {
        // Q/K path: row-major f16, ld 2048
#pragma unroll
        for (int m = 0; m < 4; m++) {
            const int row = m0 + wr * 64 + m * 16 + lg * 4;
#pragma unroll
            for (int n = 0; n < 4; n++) {
                const int col = n0 + wc * 64 + n * 16 + lr;
#pragma unroll
                for (int jj = 0; jj < 4; jj++)
                    qk[(size_t)(row + jj) * 2048 + col] = (_Float16)acc[m][n][jj];
            }
        }
    } else {
        // V path: transposed, vT[(b*1024 + vcol)][n]
#pragma unroll
        for (int m = 0; m < 4; m++) {
            const int row = m0 + wr * 64 + m * 16 + lg * 4;
            const int b = row >> 11, nn = row & 2047;
#pragma unroll
            for (int n = 0; n < 4; n++) {
                const int vcol = n0 + wc * 64 + n * 16 + lr - 2 * DIM;
                f16x4 pk;
#pragma unroll
                for (int jj = 0; jj < 4; jj++) pk[jj] = (_Float16)acc[m][n][jj];
                *reinterpret_cast<f16x4*>(&vT[(size_t)(b * 1024 + vcol) * SEQ + nn]) = pk;
            }
        }
    }
}

// ------------- out-proj GEMM: attn (4096x1024) * woutT (1024x1024) + bias -> f32 -------------
__global__ __launch_bounds__(256) void gemm_out_kernel(
    const _Float16* __restrict__ A, const _Float16* __restrict__ Bt,
    float* __restrict__ C, const float* __restrict__ bias, int N, int K) {
    __shared__ _Float16 Al[128 * 32];
    __shared__ _Float16 Bl[128 * 32];
    const int t = threadIdx.x, wv = t >> 6, lane = t & 63;
    const int lg = lane >> 4, lr = lane & 15;
    const int wr = wv >> 1, wc = wv & 1;
    const int m0 = blockIdx.y * 128, n0 = blockIdx.x * 128;

    f32x4 acc[4][4] = {};

    const int srow = t >> 2, sk = (t & 3) * 8;
    const _Float16* Ag0 = A + (size_t)(m0 + srow) * K + sk;
    const _Float16* Bg0 = Bt + (size_t)(n0 + srow) * K + sk;
    _Float16* Alw = Al + wv * 512;
    _Float16* Blw = Bl + wv * 512;

    for (int k0 = 0; k0 < K; k0 += 32) {
        __syncthreads();
        async_copy16(Alw,        Ag0 + k0);
        async_copy16(Alw + 2048, Ag0 + (size_t)64 * K + k0);
        async_copy16(Blw,        Bg0 + k0);
        async_copy16(Blw + 2048, Bg0 + (size_t)64 * K + k0);
        __syncthreads();
        f16x8 af[4], bfr[4];
#pragma unroll
        for (int m = 0; m < 4; m++)
            af[m] = *reinterpret_cast<const f16x8*>(&Al[(wr * 64 + m * 16 + lr) * 32 + lg * 8]);
#pragma unroll
        for (int n = 0; n < 4; n++)
            bfr[n] = *reinterpret_cast<const f16x8*>(&Bl[(wc * 64 + n * 16 + lr) * 32 + lg * 8]);
#pragma unroll
        for (int m = 0; m < 4; m++)
#pragma unroll
            for (int n = 0; n < 4; n++)
                acc[m][n] = __builtin_amdgcn_mfma_f32_16x16x32_f16(af[m], bfr[n], acc[m][n], 0, 0, 0);
    }

#pragma unroll
    for (int m = 0; m < 4; m++) {
        const int row = m0 + wr * 64 + m * 16 + lg * 4;
#pragma unroll
        for (int n = 0; n < 4; n++) {
            const int col = n0 + wc * 64 + n * 16 + lr;
            const float bo = bias[col];
#pragma unroll
            for (int jj = 0; jj < 4; jj++)
                C[(size_t)(row + jj) * N + col] = acc[m][n][jj] + bo;
        }
    }
}

// ------------- flash attention (swapped-operand): qk + vT -> attn (ROWS x 1024 f16) -------------
// grid (32 q-tiles, 32 b*h). block 256 = 4 waves; wave owns 16 q rows (q = lane&15); KV tile 64.
__global__ __launch_bounds__(256) void attn_fa_kernel(
    const _Float16* __restrict__ qk, const _Float16* __restrict__ vT,
    _Float16* __restrict__ attn) {
    const int bh = blockIdx.y, b = bh >> 4, h = bh & 15;
    const int q0 = blockIdx.x * 64;
    const int t = threadIdx.x, wv = t >> 6, lane = t & 63;
    const int lg = lane >> 4, lr = lane & 15;

    __shared__ _Float16 Kl[64][72];       // K tile [key][d]
    __shared__ _Float16 Vt[64][72];       // V^T tile [d][key]
    __shared__ _Float16 PT[4][16][72];    // per-wave P [q][key]

    // Q fragment (B operand: row q=lr, k=d=8*lg+j), pre-scaled by 1/8
    const size_t qrow = (size_t)(b * SEQ + q0 + wv * 16 + lr);
    const _Float16* qp = qk + qrow * 2048 + h * HD2;
    f16x8 qf0 = *reinterpret_cast<const f16x8*>(qp + lg * 8);
    f16x8 qf1 = *reinterpret_cast<const f16x8*>(qp + 32 + lg * 8);
    qf0 = qf0 * (_Float16)0.125f;
    qf1 = qf1 * (_Float16)0.125f;

    f32x4 o[4] = {};                       // O^T: lane holds d = dn*16+lg*4+jj for q = lr
    float mrun = -INFINITY, lrun = 0.f;

    const int sr = t >> 3, sc = (t & 7) * 8;
    const _Float16* kbase = qk + (size_t)(b * SEQ + sr) * 2048 + DIM + h * HD2 + sc;
    const _Float16* vbase = vT + (size_t)(bh * HD2 + sr) * SEQ + sc;

    for (int kv0 = 0; kv0 < SEQ; kv0 += 64) {
        __syncthreads();
        {   // stage K rows (keys) and V^T rows (d) — all vectorized
            const _Float16* kp = kbase + (size_t)kv0 * 2048;
            *reinterpret_cast<f16x8*>(&Kl[sr][sc])      = *reinterpret_cast<const f16x8*>(kp);
            *reinterpret_cast<f16x8*>(&Kl[sr + 32][sc]) = *reinterpret_cast<const f16x8*>(kp + (size_t)32 * 2048);
            const _Float16* vp = vbase + kv0;
            *reinterpret_cast<f16x8*>(&Vt[sr][sc])      = *reinterpret_cast<const f16x8*>(vp);
            *reinterpret_cast<f16x8*>(&Vt[sr + 32][sc]) = *reinterpret_cast<const f16x8*>(vp + (size_t)32 * SEQ);
        }
        __syncthreads();

        // S^T = K Q^T : lane holds keys {n*16+lg*4+jj} for q=lr
        f32x4 s[4];
#pragma unroll
        for (int n = 0; n < 4; n++) {
            f16x8 kf0 = *reinterpret_cast<const f16x8*>(&Kl[n * 16 + lr][lg * 8]);
            f16x8 kf1 = *reinterpret_cast<const f16x8*>(&Kl[n * 16 + lr][32 + lg * 8]);
            f32x4 z = {0.f, 0.f, 0.f, 0.f};
            z = __builtin_amdgcn_mfma_f32_16x16x32_f16(kf0, qf0, z, 0, 0, 0);
            z = __builtin_amdgcn_mfma_f32_16x16x32_f16(kf1, qf1, z, 0, 0, 0);
            s[n] = z;
        }

        // online softmax: in-lane over 16 keys, then 2 shfls across lg groups
        float m1 = -INFINITY;
#pragma unroll
        for (int n = 0; n < 4; n++)
            m1 = fmaxf(m1, fmaxf(fmaxf(s[n][0], s[n][1]), fmaxf(s[n][2], s[n][3])));
        m1 = fmaxf(m1, __shfl_xor(m1, 16));
        m1 = fmaxf(m1, __shfl_xor(m1, 32));
        const float mnew = fmaxf(mrun, m1);
        const float corr = __expf(mrun - mnew);
        mrun = mnew;
        float rsum = 0.f;
#pragma unroll
        for (int n = 0; n < 4; n++)
#pragma unroll
            for (int jj = 0; jj < 4; jj++) {
                const float p = __expf(s[n][jj] - mnew);
                s[n][jj] = p;
                rsum += p;
            }
        rsum += __shfl_xor(rsum, 16);
        rsum += __shfl_xor(rsum, 32);
        lrun = lrun * corr + rsum;
#pragma unroll
        for (int dn = 0; dn < 4; dn++) o[dn] *= corr;

        // P^T -> wave-private LDS as P[q][key] (vectorized: 4 consecutive keys per write)
#pragma unroll
        for (int n = 0; n < 4; n++) {
            f16x4 pk;
#pragma unroll
            for (int jj = 0; jj < 4; jj++) pk[jj] = (_Float16)s[n][jj];
            *reinterpret_cast<f16x4*>(&PT[wv][lr][n * 16 + lg * 4]) = pk;
        }
        f16x8 pa0 = *reinterpret_cast<const f16x8*>(&PT[wv][lr][lg * 8]);
        f16x8 pa1 = *reinterpret_cast<const f16x8*>(&PT[wv][lr][32 + lg * 8]);

        // O^T += V^T P : A = V^T rows (d), B = P rows (q)
#pragma unroll
        for (int dn = 0; dn < 4; dn++) {
            f16x8 vf0 = *reinterpret_cast<const f16x8*>(&Vt[dn * 16 + lr][lg * 8]);
            f16x8 vf1 = *reinterpret_cast<const f16x8*>(&Vt[dn * 16 + lr][32 + lg * 8]);
            o[dn] = __builtin_amdgcn_mfma_f32_16x16x32_f16(vf0, pa0, o[dn], 0, 0, 0);
            o[dn] = __builtin_amdgcn_mfma_f32_16x16x32_f16(vf1, pa1, o[dn], 0, 0, 0);
        }
    }

    // epilogue: O[q][d] = O^T/l ; lane's q = lr, d = dn*16+lg*4+jj (f16x4 per dn)
    const float inv = 1.0f / lrun;
    const size_t orow = (size_t)(b * SEQ + q0 + wv * 16 + lr);
#pragma unroll
    for (int dn = 0; dn < 4; dn++) {
        f16x4 pk;
#pragma unroll
        for (int jj = 0; jj < 4; jj++) pk[jj] = (_Float16)(o[dn][jj] * inv);
        *reinterpret_cast<f16x4*>(&attn[orow * DIM + h * HD2 + dn * 16 + lg * 4]) = pk;
    }
}

extern "C" void kernel_launch(void* const* d_in, const int* in_sizes, int n_in,
                              void* d_out, int out_size, void* d_ws, size_t ws_size,
                              hipStream_t stream) {
    const float* x     = (const float*)d_in[0];
    const float* gamma = (const float*)d_in[1];
    const float* beta  = (const float*)d_in[2];
    const float* w_qkv = (const float*)d_in[3];
    const float* w_out = (const float*)d_in[4];
    const float* b_out = (const float*)d_in[5];
    float* out = (float*)d_out;

    _Float16* ws    = (_Float16*)d_ws;
    _Float16* xn    = ws;                                  // 4096*1024
    _Float16* wqkvT = xn + (size_t)ROWS * DIM;             // 3072*1024
    _Float16* woutT = wqkvT + (size_t)QKVN * DIM;          // 1024*1024
    _Float16* qk    = woutT + (size_t)DIM * DIM;           // 4096*2048
    _Float16* vT    = qk + (size_t)ROWS * 2048;            // 2048*... (32*64)*2048
    _Float16* attnb = xn;                                  // reuse xn region

    ln_kernel<<<ROWS, 256, 0, stream>>>(x, gamma, beta, xn);
    transpose_cvt_kernel<<<dim3(QKVN / 32, DIM / 32), dim3(32, 8), 0, stream>>>(w_qkv, wqkvT, DIM, QKVN);
    transpose_cvt_kernel<<<dim3(DIM / 32, DIM / 32), dim3(32, 8), 0, stream>>>(w_out, woutT, DIM, DIM);
    gemm_qkv_kernel<<<dim3(QKVN / 128, ROWS / 128), 256, 0, stream>>>(xn, wqkvT, qk, vT, DIM);
    attn_fa_kernel<<<dim3(SEQ / 64, 32), 256, 0, stream>>>(qk, vT, attnb);
    gemm_out_kernel<<<dim3(DIM / 128, ROWS / 128), 256, 0, stream>>>(attnb, woutT, out, b_out, DIM, DIM);
}

// Round 3
// 217.202 us; speedup vs baseline: 1.4571x; 1.0596x over previous
//
#include <hip/hip_runtime.h>
#include <hip/hip_bf16.h>

// Fused: LayerNorm -> QKV proj (V written transposed) -> 16-head attention -> out proj + bias.

typedef _Float16 f16x8 __attribute__((ext_vector_type(8)));
typedef _Float16 f16x4 __attribute__((ext_vector_type(4)));
typedef float    f32x4 __attribute__((ext_vector_type(4)));

#define DIM   1024
#define NH    16
#define HD2   64
#define SEQ   2048
#define ROWS  4096   // b*n = 2*2048
#define QKVN  3072

__device__ __forceinline__ void async_copy16(void* lds, const void* gsrc) {
    __builtin_amdgcn_global_load_lds(
        (const __attribute__((address_space(1))) unsigned int*)gsrc,
        (__attribute__((address_space(3))) unsigned int*)lds, 16, 0, 0);
}

// ---------------- LayerNorm: fp32 (ROWS x DIM) -> f16 ----------------
__global__ __launch_bounds__(256) void ln_kernel(
    const float* __restrict__ x, const float* __restrict__ gamma,
    const float* __restrict__ beta, _Float16* __restrict__ xn) {
    const int row = blockIdx.x;
    const int t = threadIdx.x;
    const float4 v = reinterpret_cast<const float4*>(x + (size_t)row * DIM)[t];
    float s1 = v.x + v.y + v.z + v.w;
    float s2 = v.x * v.x + v.y * v.y + v.z * v.z + v.w * v.w;
    for (int off = 32; off; off >>= 1) {
        s1 += __shfl_down(s1, off);
        s2 += __shfl_down(s2, off);
    }
    __shared__ float red[8];
    const int wv = t >> 6, lane = t & 63;
    if (lane == 0) { red[wv * 2] = s1; red[wv * 2 + 1] = s2; }
    __syncthreads();
    s1 = red[0] + red[2] + red[4] + red[6];
    s2 = red[1] + red[3] + red[5] + red[7];
    const float mu = s1 * (1.0f / DIM);
    const float var = s2 * (1.0f / DIM) - mu * mu;
    const float rstd = rsqrtf(var + 1e-5f);
    const float4 g = reinterpret_cast<const float4*>(gamma)[t];
    const float4 bb = reinterpret_cast<const float4*>(beta)[t];
    f16x4 o;
    o[0] = (_Float16)((v.x - mu) * rstd * g.x + bb.x);
    o[1] = (_Float16)((v.y - mu) * rstd * g.y + bb.y);
    o[2] = (_Float16)((v.z - mu) * rstd * g.z + bb.z);
    o[3] = (_Float16)((v.w - mu) * rstd * g.w + bb.w);
    reinterpret_cast<f16x4*>(xn + (size_t)row * DIM)[t] = o;
}

// ------------- transpose + fp32->f16: in (R x C) -> out (C x R) -------------
__global__ __launch_bounds__(256) void transpose_cvt_kernel(
    const float* __restrict__ in, _Float16* __restrict__ out, int R, int C) {
    __shared__ float tile[32][33];
    const int c0 = blockIdx.x * 32, r0 = blockIdx.y * 32;
    const int tx = threadIdx.x, ty = threadIdx.y;  // (32, 8)
#pragma unroll
    for (int i = 0; i < 4; i++)
        tile[ty + i * 8][tx] = in[(size_t)(r0 + ty + i * 8) * C + c0 + tx];
    __syncthreads();
#pragma unroll
    for (int i = 0; i < 4; i++)
        out[(size_t)(c0 + ty + i * 8) * R + r0 + tx] = (_Float16)tile[tx][ty + i * 8];
}

// ------------- QKV GEMM: xn (4096x1024) * wqkvT (3072x1024), 2-phase dbuf -------------
// Q,K cols (<2048) -> qk[row][col] (ld 2048). V cols (>=2048) -> vT[bh*64+d][n].
__global__ __launch_bounds__(256) void gemm_qkv_kernel(
    const _Float16* __restrict__ A, const _Float16* __restrict__ Bt,
    _Float16* __restrict__ qk, _Float16* __restrict__ vT, int K) {
    __shared__ _Float16 Al[2][128 * 32];
    __shared__ _Float16 Bl[2][128 * 32];
    const int t = threadIdx.x, wv = t >> 6, lane = t & 63;
    const int lg = lane >> 4, lr = lane & 15;
    const int wr = wv >> 1, wc = wv & 1;
    const int m0 = blockIdx.y * 128, n0 = blockIdx.x * 128;

    f32x4 acc[4][4] = {};

    const int srow = t >> 2, sk = (t & 3) * 8;
    const _Float16* Ag0 = A + (size_t)(m0 + srow) * K + sk;
    const _Float16* Bg0 = Bt + (size_t)(n0 + srow) * K + sk;

    auto STAGE = [&](int buf, int k0) {
        _Float16* Alw = &Al[buf][wv * 512];
        _Float16* Blw = &Bl[buf][wv * 512];
        async_copy16(Alw,        Ag0 + k0);
        async_copy16(Alw + 2048, Ag0 + (size_t)64 * K + k0);
        async_copy16(Blw,        Bg0 + k0);
        async_copy16(Blw + 2048, Bg0 + (size_t)64 * K + k0);
    };

    STAGE(0, 0);
    asm volatile("s_waitcnt vmcnt(0)" ::: "memory");
    __builtin_amdgcn_s_barrier();
    int cur = 0;
    for (int k0 = 0; k0 < K; k0 += 32) {
        if (k0 + 32 < K) STAGE(cur ^ 1, k0 + 32);
        const _Float16* Ab = &Al[cur][0];
        const _Float16* Bb = &Bl[cur][0];
        f16x8 af[4], bfr[4];
#pragma unroll
        for (int m = 0; m < 4; m++)
            af[m] = *reinterpret_cast<const f16x8*>(&Ab[(wr * 64 + m * 16 + lr) * 32 + lg * 8]);
#pragma unroll
        for (int n = 0; n < 4; n++)
            bfr[n] = *reinterpret_cast<const f16x8*>(&Bb[(wc * 64 + n * 16 + lr) * 32 + lg * 8]);
#pragma unroll
        for (int m = 0; m < 4; m++)
#pragma unroll
            for (int n = 0; n < 4; n++)
                acc[m][n] = __builtin_amdgcn_mfma_f32_16x16x32_f16(af[m], bfr[n], acc[m][n], 0, 0, 0);
        asm volatile("s_waitcnt vmcnt(0)" ::: "memory");
        __builtin_amdgcn_s_barrier();
        cur ^= 1;
    }

    if (n0 < 2 * DIM) {
#pragma unroll
        for (int m = 0; m < 4; m++) {
            const int row = m0 + wr * 64 + m * 16 + lg * 4;
#pragma unroll
            for (int n = 0; n < 4; n++) {
                const int col = n0 + wc * 64 + n * 16 + lr;
#pragma unroll
                for (int jj = 0; jj < 4; jj++)
                    qk[(size_t)(row + jj) * 2048 + col] = (_Float16)acc[m][n][jj];
            }
        }
    } else {
#pragma unroll
        for (int m = 0; m < 4; m++) {
            const int row = m0 + wr * 64 + m * 16 + lg * 4;
            const int b = row >> 11, nn = row & 2047;
#pragma unroll
            for (int n = 0; n < 4; n++) {
                const int vcol = n0 + wc * 64 + n * 16 + lr - 2 * DIM;
                f16x4 pk;
#pragma unroll
                for (int jj = 0; jj < 4; jj++) pk[jj] = (_Float16)acc[m][n][jj];
                *reinterpret_cast<f16x4*>(&vT[(size_t)(b * 1024 + vcol) * SEQ + nn]) = pk;
            }
        }
    }
}

// ------------- out-proj GEMM: attn (4096x1024) * woutT (1024x1024) + bias -> f32 -------------
// tile 128(M) x 64(N), 2-phase dbuf; grid (16, 32) = 512 blocks for occupancy.
__global__ __launch_bounds__(256) void gemm_out_kernel(
    const _Float16* __restrict__ A, const _Float16* __restrict__ Bt,
    float* __restrict__ C, const float* __restrict__ bias, int N, int K) {
    __shared__ _Float16 Al[2][128 * 32];
    __shared__ _Float16 Bl[2][64 * 32];
    const int t = threadIdx.x, wv = t >> 6, lane = t & 63;
    const int lg = lane >> 4, lr = lane & 15;
    const int wr = wv >> 1, wc = wv & 1;
    const int m0 = blockIdx.y * 128, n0 = blockIdx.x * 64;

    f32x4 acc[4][2] = {};

    const int srow = t >> 2, sk = (t & 3) * 8;
    const _Float16* Ag0 = A + (size_t)(m0 + srow) * K + sk;
    const _Float16* Bg0 = Bt + (size_t)(n0 + srow) * K + sk;   // srow 0..63 covers B tile

    auto STAGE = [&](int buf, int k0) {
        _Float16* Alw = &Al[buf][wv * 512];
        _Float16* Blw = &Bl[buf][wv * 512];
        async_copy16(Alw,        Ag0 + k0);
        async_copy16(Alw + 2048, Ag0 + (size_t)64 * K + k0);
        async_copy16(Blw,        Bg0 + k0);
    };

    STAGE(0, 0);
    asm volatile("s_waitcnt vmcnt(0)" ::: "memory");
    __builtin_amdgcn_s_barrier();
    int cur = 0;
    for (int k0 = 0; k0 < K; k0 += 32) {
        if (k0 + 32 < K) STAGE(cur ^ 1, k0 + 32);
        const _Float16* Ab = &Al[cur][0];
        const _Float16* Bb = &Bl[cur][0];
        f16x8 af[4], bfr[2];
#pragma unroll
        for (int m = 0; m < 4; m++)
            af[m] = *reinterpret_cast<const f16x8*>(&Ab[(wr * 64 + m * 16 + lr) * 32 + lg * 8]);
#pragma unroll
        for (int n = 0; n < 2; n++)
            bfr[n] = *reinterpret_cast<const f16x8*>(&Bb[(wc * 32 + n * 16 + lr) * 32 + lg * 8]);
#pragma unroll
        for (int m = 0; m < 4; m++)
#pragma unroll
            for (int n = 0; n < 2; n++)
                acc[m][n] = __builtin_amdgcn_mfma_f32_16x16x32_f16(af[m], bfr[n], acc[m][n], 0, 0, 0);
        asm volatile("s_waitcnt vmcnt(0)" ::: "memory");
        __builtin_amdgcn_s_barrier();
        cur ^= 1;
    }

#pragma unroll
    for (int m = 0; m < 4; m++) {
        const int row = m0 + wr * 64 + m * 16 + lg * 4;
#pragma unroll
        for (int n = 0; n < 2; n++) {
            const int col = n0 + wc * 32 + n * 16 + lr;
            const float bo = bias[col];
#pragma unroll
            for (int jj = 0; jj < 4; jj++)
                C[(size_t)(row + jj) * N + col] = acc[m][n][jj] + bo;
        }
    }
}

// ------------- flash attention (swapped-operand, reg-prefetch pipeline) -------------
// 1D grid 1024 blocks, XCD-swizzled. block 256 = 4 waves; wave owns 16 q rows; KV tile 64.
__global__ __launch_bounds__(256) void attn_fa_kernel(
    const _Float16* __restrict__ qk, const _Float16* __restrict__ vT,
    _Float16* __restrict__ attn) {
    const int id = blockIdx.x;
    const int nid = (id & 7) * 128 + (id >> 3);     // bijective: 1024 = 8 XCD x 128
    const int bh = nid >> 5, b = bh >> 4, h = bh & 15;
    const int q0 = (nid & 31) * 64;
    const int t = threadIdx.x, wv = t >> 6, lane = t & 63;
    const int lg = lane >> 4, lr = lane & 15;

    __shared__ _Float16 Kl[64][72];       // K tile [key][d]
    __shared__ _Float16 Vt[64][72];       // V^T tile [d][key]
    __shared__ _Float16 PT[4][16][72];    // per-wave P [q][key]

    // Q fragment (B operand: col q=lr, k=d=8*lg+j), pre-scaled by 1/8
    const size_t qrow = (size_t)(b * SEQ + q0 + wv * 16 + lr);
    const _Float16* qp = qk + qrow * 2048 + h * HD2;
    f16x8 qf0 = *reinterpret_cast<const f16x8*>(qp + lg * 8);
    f16x8 qf1 = *reinterpret_cast<const f16x8*>(qp + 32 + lg * 8);
    qf0 = qf0 * (_Float16)0.125f;
    qf1 = qf1 * (_Float16)0.125f;

    f32x4 o[4] = {};                       // O^T: lane holds d = dn*16+lg*4+jj for q = lr
    float mrun = -INFINITY, lrun = 0.f;

    const int sr = t >> 3, sc = (t & 7) * 8;
    const _Float16* kbase = qk + (size_t)(b * SEQ + sr) * 2048 + DIM + h * HD2 + sc;
    const _Float16* vbase = vT + (size_t)(bh * HD2 + sr) * SEQ + sc;

    // prologue: prefetch tile 0 into regs
    f16x8 rk0 = *reinterpret_cast<const f16x8*>(kbase);
    f16x8 rk1 = *reinterpret_cast<const f16x8*>(kbase + (size_t)32 * 2048);
    f16x8 rv0 = *reinterpret_cast<const f16x8*>(vbase);
    f16x8 rv1 = *reinterpret_cast<const f16x8*>(vbase + (size_t)32 * SEQ);

    for (int kv0 = 0; kv0 < SEQ; kv0 += 64) {
        __builtin_amdgcn_s_barrier();   // prev compute consumed K/V LDS (reads drained pre-MFMA)
        *reinterpret_cast<f16x8*>(&Kl[sr][sc])      = rk0;
        *reinterpret_cast<f16x8*>(&Kl[sr + 32][sc]) = rk1;
        *reinterpret_cast<f16x8*>(&Vt[sr][sc])      = rv0;
        *reinterpret_cast<f16x8*>(&Vt[sr + 32][sc]) = rv1;
        if (kv0 + 64 < SEQ) {           // issue next-tile loads; fly during compute
            const _Float16* kp = kbase + (size_t)(kv0 + 64) * 2048;
            const _Float16* vp = vbase + (kv0 + 64);
            rk0 = *reinterpret_cast<const f16x8*>(kp);
            rk1 = *reinterpret_cast<const f16x8*>(kp + (size_t)32 * 2048);
            rv0 = *reinterpret_cast<const f16x8*>(vp);
            rv1 = *reinterpret_cast<const f16x8*>(vp + (size_t)32 * SEQ);
        }
        asm volatile("s_waitcnt lgkmcnt(0)" ::: "memory");   // own ds_writes done
        __builtin_amdgcn_s_barrier();                        // all writes visible

        // S^T = K Q^T : lane holds keys {n*16+lg*4+jj} for q=lr
        f32x4 s[4];
#pragma unroll
        for (int n = 0; n < 4; n++) {
            f16x8 kf0 = *reinterpret_cast<const f16x8*>(&Kl[n * 16 + lr][lg * 8]);
            f16x8 kf1 = *reinterpret_cast<const f16x8*>(&Kl[n * 16 + lr][32 + lg * 8]);
            f32x4 z = {0.f, 0.f, 0.f, 0.f};
            __builtin_amdgcn_s_setprio(1);
            z = __builtin_amdgcn_mfma_f32_16x16x32_f16(kf0, qf0, z, 0, 0, 0);
            z = __builtin_amdgcn_mfma_f32_16x16x32_f16(kf1, qf1, z, 0, 0, 0);
            __builtin_amdgcn_s_setprio(0);
            s[n] = z;
        }

        // online softmax with defer-max (T13): in-lane over 16 keys + 2 shfls
        float m1 = fmaxf(fmaxf(s[0][0], s[0][1]), fmaxf(s[0][2], s[0][3]));
#pragma unroll
        for (int n = 1; n < 4; n++)
            m1 = fmaxf(m1, fmaxf(fmaxf(s[n][0], s[n][1]), fmaxf(s[n][2], s[n][3])));
        m1 = fmaxf(m1, __shfl_xor(m1, 16));
        m1 = fmaxf(m1, __shfl_xor(m1, 32));
        if (!__all(m1 - mrun <= 8.f)) {
            const float mnew = fmaxf(mrun, m1);
            const float corr = __expf(mrun - mnew);
            mrun = mnew;
            lrun *= corr;
#pragma unroll
            for (int dn = 0; dn < 4; dn++) o[dn] *= corr;
        }
        float rsum = 0.f;
#pragma unroll
        for (int n = 0; n < 4; n++)
#pragma unroll
            for (int jj = 0; jj < 4; jj++) {
                const float p = __expf(s[n][jj] - mrun);
                s[n][jj] = p;
                rsum += p;
            }
        rsum += __shfl_xor(rsum, 16);
        rsum += __shfl_xor(rsum, 32);
        lrun += rsum;

        // P^T -> wave-private LDS as P[q][key] (b64 writes, 4 consecutive keys)
#pragma unroll
        for (int n = 0; n < 4; n++) {
            f16x4 pk;
#pragma unroll
            for (int jj = 0; jj < 4; jj++) pk[jj] = (_Float16)s[n][jj];
            *reinterpret_cast<f16x4*>(&PT[wv][lr][n * 16 + lg * 4]) = pk;
        }
        f16x8 pa0 = *reinterpret_cast<const f16x8*>(&PT[wv][lr][lg * 8]);
        f16x8 pa1 = *reinterpret_cast<const f16x8*>(&PT[wv][lr][32 + lg * 8]);

        // O^T += V^T P : A = V^T rows (d), B = P rows (q)
#pragma unroll
        for (int dn = 0; dn < 4; dn++) {
            f16x8 vf0 = *reinterpret_cast<const f16x8*>(&Vt[dn * 16 + lr][lg * 8]);
            f16x8 vf1 = *reinterpret_cast<const f16x8*>(&Vt[dn * 16 + lr][32 + lg * 8]);
            __builtin_amdgcn_s_setprio(1);
            o[dn] = __builtin_amdgcn_mfma_f32_16x16x32_f16(vf0, pa0, o[dn], 0, 0, 0);
            o[dn] = __builtin_amdgcn_mfma_f32_16x16x32_f16(vf1, pa1, o[dn], 0, 0, 0);
            __builtin_amdgcn_s_setprio(0);
        }
    }

    // epilogue: O[q][d] = O^T/l ; lane's q = lr, d = dn*16+lg*4+jj (f16x4 per dn)
    const float inv = 1.0f / lrun;
    const size_t orow = (size_t)(b * SEQ + q0 + wv * 16 + lr);
#pragma unroll
    for (int dn = 0; dn < 4; dn++) {
        f16x4 pk;
#pragma unroll
        for (int jj = 0; jj < 4; jj++) pk[jj] = (_Float16)(o[dn][jj] * inv);
        *reinterpret_cast<f16x4*>(&attn[orow * DIM + h * HD2 + dn * 16 + lg * 4]) = pk;
    }
}

extern "C" void kernel_launch(void* const* d_in, const int* in_sizes, int n_in,
                              void* d_out, int out_size, void* d_ws, size_t ws_size,
                              hipStream_t stream) {
    const float* x     = (const float*)d_in[0];
    const float* gamma = (const float*)d_in[1];
    const float* beta  = (const float*)d_in[2];
    const float* w_qkv = (const float*)d_in[3];
    const float* w_out = (const float*)d_in[4];
    const float* b_out = (const float*)d_in[5];
    float* out = (float*)d_out;

    _Float16* ws    = (_Float16*)d_ws;
    _Float16* xn    = ws;                                  // 4096*1024
    _Float16* wqkvT = xn + (size_t)ROWS * DIM;             // 3072*1024
    _Float16* woutT = wqkvT + (size_t)QKVN * DIM;          // 1024*1024
    _Float16* qk    = woutT + (size_t)DIM * DIM;           // 4096*2048
    _Float16* vT    = qk + (size_t)ROWS * 2048;            // (32*64)*2048
    _Float16* attnb = xn;                                  // reuse xn region

    ln_kernel<<<ROWS, 256, 0, stream>>>(x, gamma, beta, xn);
    transpose_cvt_kernel<<<dim3(QKVN / 32, DIM / 32), dim3(32, 8), 0, stream>>>(w_qkv, wqkvT, DIM, QKVN);
    transpose_cvt_kernel<<<dim3(DIM / 32, DIM / 32), dim3(32, 8), 0, stream>>>(w_out, woutT, DIM, DIM);
    gemm_qkv_kernel<<<dim3(QKVN / 128, ROWS / 128), 256, 0, stream>>>(xn, wqkvT, qk, vT, DIM);
    attn_fa_kernel<<<1024, 256, 0, stream>>>(qk, vT, attnb);
    gemm_out_kernel<<<dim3(DIM / 64, ROWS / 128), 256, 0, stream>>>(attnb, woutT, out, b_out, DIM, DIM);
}